// Round 1
// baseline (22605.133 us; speedup 1.0000x reference)
//
#include <hip/hip_runtime.h>
#include <hip/hip_bf16.h>
#include <stdint.h>

// Problem constants (from reference)
#define BATCH   8192
#define IN_DIM  1024
#define N_HID   2048
#define OUT_DIM 256
#define SRC_DIM (IN_DIM + N_HID)   // 3072

// Tiling
#define C       32                  // source columns per chunk
#define RB      64                  // rows per row-block (= rows per wave)
#define SEG_STRIDE 2112             // 64 u8 counts + up to 64*32 u8 edges

#define S1_RB (N_HID / RB)          // 32
#define S1_CH (IN_DIM / C)          // 32
#define S2_RB (OUT_DIM / RB)        // 4
#define S2_CH (SRC_DIM / C)         // 96
#define NSEG1 (S1_RB * S1_CH)       // 1024
#define NSEG2 (S2_RB * S2_CH)       // 384

// ---------------------------------------------------------------------------
// Prep: build per-(row-block, chunk) edge segments from mat (int codes 0..4).
// Segment layout: u8 counts[64]; then for each row r ascending, cnt[r] edge
// bytes e = (c_local<<2) | (t-1).  e doubles as the A-tile index in consumers.
// One wave per segment.
// ---------------------------------------------------------------------------
__global__ void k_prep(const int* __restrict__ mat,
                       uint8_t* __restrict__ seg1,
                       uint8_t* __restrict__ seg2) {
    int wid  = (blockIdx.x * blockDim.x + threadIdx.x) >> 6;
    int lane = threadIdx.x & 63;
    if (wid >= NSEG1 + NSEG2) return;

    int row0, col0;
    uint8_t* seg;
    if (wid < NSEG1) {
        int rb = wid / S1_CH, ch = wid % S1_CH;
        row0 = rb * RB;            col0 = ch * C;
        seg  = seg1 + (size_t)wid * SEG_STRIDE;
    } else {
        int s  = wid - NSEG1;
        int rb = s / S2_CH, ch = s % S2_CH;
        row0 = N_HID + rb * RB;    col0 = ch * C;
        seg  = seg2 + (size_t)s * SEG_STRIDE;
    }

    const int* mrow = mat + (size_t)(row0 + lane) * SRC_DIM + col0;

    // pass 1: count
    int cnt = 0;
    for (int c = 0; c < C; c++)
        if (mrow[c] != 0) cnt++;

    // inclusive scan over 64 lanes
    int incl = cnt;
    #pragma unroll
    for (int d = 1; d < 64; d <<= 1) {
        int n = __shfl_up(incl, d, 64);
        if (lane >= d) incl += n;
    }
    int excl = incl - cnt;

    seg[lane] = (uint8_t)cnt;

    // pass 2: write edge bytes (L1-hot re-read of mrow)
    uint8_t* ep = seg + 64 + excl;
    int j = 0;
    for (int c = 0; c < C; c++) {
        int code = mrow[c];
        if (code != 0) {
            ep[j] = (uint8_t)((c << 2) | (code - 1));
            j++;
        }
    }
}

// activation tile write helper: v = w*src; A[c][t][lane], t: 0=id,1=relu,2=tanh,3=sigmoid
__device__ __forceinline__ void write_acts(float* A, int c, int lane, float v) {
    float e2 = __expf(2.0f * v);
    float en = __expf(-v);
    A[(c * 4 + 0) * 64 + lane] = v;
    A[(c * 4 + 1) * 64 + lane] = fmaxf(v, 0.0f);
    A[(c * 4 + 2) * 64 + lane] = 1.0f - 2.0f / (e2 + 1.0f);   // tanh
    A[(c * 4 + 3) * 64 + lane] = 1.0f / (1.0f + en);          // sigmoid
}

// ---------------------------------------------------------------------------
// Stage 1: hidden[b, r] for r in this block's 512-row slab.
// Block: 512 threads = 8 waves x 64 rows; lanes = 64 batch elements.
// Grid: (128 batch tiles, 4 row splits).
// ---------------------------------------------------------------------------
__global__ __launch_bounds__(512, 4) void k_hid(const float* __restrict__ x,
                                                const float* __restrict__ wp,
                                                const uint8_t* __restrict__ seg1,
                                                __hip_bfloat16* __restrict__ hidden) {
    __shared__ float A[C * 4 * 64];        // 32 KB: [c][t][lane]
    __shared__ float xs[64][C + 1];        // 8.4 KB, padded

    const float w = wp[0];
    const int tile   = blockIdx.x;         // 0..127
    const int rsplit = blockIdx.y;         // 0..3
    const int lane   = threadIdx.x & 63;
    const int wv     = threadIdx.x >> 6;   // 0..7
    const int row_base = rsplit * 512 + wv * RB;  // hidden row for acc[0]
    const int rb       = row_base / RB;           // segment row-block id

    float acc[RB];
    #pragma unroll
    for (int r = 0; r < RB; r++) acc[r] = 0.0f;

    #pragma unroll 1
    for (int ch = 0; ch < S1_CH; ch++) {
        __syncthreads();
        // stage x tile: 64 b x 32 c, coalesced along c
        {
            int cc = threadIdx.x & 31;
            int bb = threadIdx.x >> 5;     // 0..15
            #pragma unroll
            for (int k = 0; k < 4; k++) {
                int bbb = bb + 16 * k;
                xs[bbb][cc] = x[(size_t)(tile * 64 + bbb) * IN_DIM + ch * C + cc];
            }
        }
        __syncthreads();
        // activations: each wave owns 4 columns
        #pragma unroll
        for (int j = 0; j < 4; j++) {
            int c = wv * 4 + j;
            write_acts(A, c, lane, w * xs[lane][c]);
        }
        __syncthreads();
        // edge accumulation (wave-uniform control flow)
        const uint8_t* sg = seg1 + (size_t)(rb * S1_CH + ch) * SEG_STRIDE;
        int off = 64;
        #pragma unroll
        for (int r = 0; r < RB; r++) {
            int cnt = sg[r];
            float a = acc[r];
            for (int j2 = 0; j2 < cnt; j2++) {
                int e = sg[off + j2];
                a += A[e * 64 + lane];
            }
            off += cnt;
            acc[r] = a;
        }
    }

    // store hidden slab (bf16)
    const int b = tile * 64 + lane;
    #pragma unroll
    for (int r = 0; r < RB; r++)
        hidden[(size_t)b * N_HID + row_base + r] = __float2bfloat16(acc[r]);
}

// ---------------------------------------------------------------------------
// Stage 2: out[b, r], r in 0..255.  Block: 256 threads = 4 waves x 64 rows.
// Grid: (128 batch tiles, 8 chunk-groups of 12 chunks).  Partials -> atomicAdd.
// ---------------------------------------------------------------------------
__global__ __launch_bounds__(256, 4) void k_out(const float* __restrict__ x,
                                                const __hip_bfloat16* __restrict__ hidden,
                                                const float* __restrict__ wp,
                                                const uint8_t* __restrict__ seg2,
                                                float* __restrict__ out) {
    __shared__ float A[C * 4 * 64];
    __shared__ float xs[64][C + 1];

    const float w = wp[0];
    const int tile = blockIdx.x;           // 0..127
    const int cg   = blockIdx.y;           // 0..7
    const int lane = threadIdx.x & 63;
    const int wv   = threadIdx.x >> 6;     // 0..3  (= row-block id)

    float acc[RB];
    #pragma unroll
    for (int r = 0; r < RB; r++) acc[r] = 0.0f;

    #pragma unroll 1
    for (int cj = 0; cj < 12; cj++) {
        int ch   = cg * 12 + cj;
        int col0 = ch * C;
        __syncthreads();
        // stage src tile (x or hidden)
        {
            int cc = threadIdx.x & 31;
            int bb = threadIdx.x >> 5;     // 0..7
            #pragma unroll
            for (int k = 0; k < 8; k++) {
                int bbb  = bb + 8 * k;
                int gcol = col0 + cc;
                float v;
                if (gcol < IN_DIM)
                    v = x[(size_t)(tile * 64 + bbb) * IN_DIM + gcol];
                else
                    v = __bfloat162float(hidden[(size_t)(tile * 64 + bbb) * N_HID + (gcol - IN_DIM)]);
                xs[bbb][cc] = v;
            }
        }
        __syncthreads();
        // activations: each wave owns 8 columns
        #pragma unroll
        for (int j = 0; j < 8; j++) {
            int c = wv * 8 + j;
            write_acts(A, c, lane, w * xs[lane][c]);
        }
        __syncthreads();
        // edge accumulation
        const uint8_t* sg = seg2 + (size_t)(wv * S2_CH + ch) * SEG_STRIDE;
        int off = 64;
        #pragma unroll
        for (int r = 0; r < RB; r++) {
            int cnt = sg[r];
            float a = acc[r];
            for (int j2 = 0; j2 < cnt; j2++) {
                int e = sg[off + j2];
                a += A[e * 64 + lane];
            }
            off += cnt;
            acc[r] = a;
        }
    }

    const int b = tile * 64 + lane;
    #pragma unroll
    for (int r = 0; r < RB; r++)
        atomicAdd(&out[(size_t)b * OUT_DIM + wv * RB + r], acc[r]);
}

// ---------------------------------------------------------------------------
extern "C" void kernel_launch(void* const* d_in, const int* in_sizes, int n_in,
                              void* d_out, int out_size, void* d_ws, size_t ws_size,
                              hipStream_t stream) {
    const float* x   = (const float*)d_in[0];
    const float* w   = (const float*)d_in[1];
    const int*   mat = (const int*)d_in[2];
    float* out = (float*)d_out;

    uint8_t* ws = (uint8_t*)d_ws;
    __hip_bfloat16* hidden = (__hip_bfloat16*)ws;                      // 8192*2048*2 = 33.5 MB
    uint8_t* seg1 = ws + (size_t)BATCH * N_HID * sizeof(__hip_bfloat16);
    uint8_t* seg2 = seg1 + (size_t)NSEG1 * SEG_STRIDE;                 // +2.16 MB
    // total ws use ~36.5 MB                                            // +0.81 MB

    (void)ws_size; (void)in_sizes; (void)n_in;

    hipMemsetAsync(d_out, 0, (size_t)out_size * sizeof(float), stream);

    {
        int nseg = NSEG1 + NSEG2;                 // 1408 waves
        int nblk = (nseg + 3) / 4;                // 4 waves / 256-thread block
        k_prep<<<nblk, 256, 0, stream>>>(mat, seg1, seg2);
    }
    {
        dim3 g(BATCH / 64, 4);                    // 128 x 4 = 512 blocks
        k_hid<<<g, 512, 0, stream>>>(x, w, seg1, hidden);
    }
    {
        dim3 g(BATCH / 64, 8);                    // 128 x 8 = 1024 blocks
        k_out<<<g, 256, 0, stream>>>(x, hidden, w, seg2, out);
    }
}

// Round 2
// 1011.154 us; speedup vs baseline: 22.3558x; 22.3558x over previous
//
#include <hip/hip_runtime.h>
#include <hip/hip_bf16.h>
#include <stdint.h>

// Problem constants
#define BATCH   8192
#define IN_DIM  1024
#define N_HID   2048
#define OUT_DIM 256
#define SRC_DIM 3072

// Tiling
#define C   32                    // source columns per chunk
#define RB  32                    // rows per row-block (= rows per wave)
#define S1_CH (IN_DIM / C)        // 32
#define S1_RB (N_HID / RB)        // 64
#define S2_CH (SRC_DIM / C)       // 96
#define S2_RB (OUT_DIM / RB)      // 8

// Segment format: per (row-block rb, chunk ch, local row r) one uint4 =
// {mask_t1, mask_t2, mask_t3, mask_t4}, bit c set => edge (row, col0+c) with
// that activation type.  Index: seg[(rb*NCH + ch)*RB + r].

// ---------------------------------------------------------------------------
// Prep: one wave per (row, 64-col pair). Coalesced mat read + __ballot builds
// the per-type masks for two chunks at once; lanes 0 and 32 write the uint4s.
// ---------------------------------------------------------------------------
__global__ void k_prep(const int* __restrict__ mat,
                       uint4* __restrict__ seg1,
                       uint4* __restrict__ seg2) {
    const int W1 = N_HID * (IN_DIM / 64);    // 32768
    const int W2 = OUT_DIM * (SRC_DIM / 64); // 12288
    int wid  = (blockIdx.x * blockDim.x + threadIdx.x) >> 6;
    int lane = threadIdx.x & 63;
    if (wid >= W1 + W2) return;

    int row, p, nch;
    uint4* seg;
    const int* mrow;
    if (wid < W1) {
        row = wid >> 4; p = wid & 15; nch = S1_CH; seg = seg1;
        mrow = mat + (size_t)row * SRC_DIM;
    } else {
        int w2 = wid - W1;
        row = w2 / 48; p = w2 % 48; nch = S2_CH; seg = seg2;
        mrow = mat + (size_t)(N_HID + row) * SRC_DIM;
    }

    int code = mrow[p * 64 + lane];
    unsigned long long b1 = __ballot(code == 1);
    unsigned long long b2 = __ballot(code == 2);
    unsigned long long b3 = __ballot(code == 3);
    unsigned long long b4 = __ballot(code == 4);

    if ((lane & 31) == 0) {
        int half = lane >> 5;
        int ch   = 2 * p + half;
        int rb   = row >> 5, r = row & 31;
        uint4 v;
        v.x = (uint32_t)(b1 >> (half * 32));
        v.y = (uint32_t)(b2 >> (half * 32));
        v.z = (uint32_t)(b3 >> (half * 32));
        v.w = (uint32_t)(b4 >> (half * 32));
        seg[(size_t)(rb * nch + ch) * RB + r] = v;
    }
}

// A-tile layout: As[(t*C + c)*64 + lane] so the type offset t*8192B folds into
// the ds_read immediate. t: 0=id,1=relu,2=tanh,3=sigmoid
__device__ __forceinline__ void write_acts(float* As, int c, int lane, float v) {
    float e2 = __expf(2.0f * v);
    float en = __expf(-v);
    As[(0 * C + c) * 64 + lane] = v;
    As[(1 * C + c) * 64 + lane] = fmaxf(v, 0.0f);
    As[(2 * C + c) * 64 + lane] = 1.0f - 2.0f / (e2 + 1.0f);   // tanh
    As[(3 * C + c) * 64 + lane] = 1.0f / (1.0f + en);          // sigmoid
}

// Edge accumulation for one wave-chunk: masks come in via one coalesced uint4
// load (lane&31 = row), broadcast per row with v_readlane; while-loops are
// scalar (s_ff1 + clear), per edge: addr VALU + ds_read_b32 + v_add.
#define EDGE_LOOP(SEGPTR, SEGIDX)                                              \
    {                                                                          \
        uint4 mr = (SEGPTR)[(size_t)(SEGIDX) * RB + (lane & 31)];              \
        _Pragma("unroll")                                                      \
        for (int r = 0; r < RB; r++) {                                         \
            uint32_t m0 = (uint32_t)__builtin_amdgcn_readlane((int)mr.x, r);   \
            uint32_t m1 = (uint32_t)__builtin_amdgcn_readlane((int)mr.y, r);   \
            uint32_t m2 = (uint32_t)__builtin_amdgcn_readlane((int)mr.z, r);   \
            uint32_t m3 = (uint32_t)__builtin_amdgcn_readlane((int)mr.w, r);   \
            float a = acc[r];                                                  \
            while (m0) { int c = __builtin_ctz(m0); m0 &= m0 - 1;              \
                         a += As[(0 * C + c) * 64 + lane]; }                   \
            while (m1) { int c = __builtin_ctz(m1); m1 &= m1 - 1;              \
                         a += As[(1 * C + c) * 64 + lane]; }                   \
            while (m2) { int c = __builtin_ctz(m2); m2 &= m2 - 1;              \
                         a += As[(2 * C + c) * 64 + lane]; }                   \
            while (m3) { int c = __builtin_ctz(m3); m3 &= m3 - 1;              \
                         a += As[(3 * C + c) * 64 + lane]; }                   \
            acc[r] = a;                                                        \
        }                                                                      \
    }

// ---------------------------------------------------------------------------
// Stage 1: block = 512 thr = 8 waves x 32 rows = 256 rows; lanes = 64 batch.
// Grid (128 batch tiles, 8 row splits). hidden stored TRANSPOSED [row][batch]
// so the bf16 store (and k_out's read) is lane-coalesced.
// ---------------------------------------------------------------------------
__global__ __launch_bounds__(512, 4) void k_hid(const float* __restrict__ x,
                                                const float* __restrict__ wp,
                                                const uint4* __restrict__ seg1,
                                                __hip_bfloat16* __restrict__ hidden_t) {
    __shared__ float As[4 * C * 64];       // 32 KB
    __shared__ float xs[64][C + 1];        // 8.4 KB

    const float w  = wp[0];
    const int tile = blockIdx.x;           // 0..127
    const int lane = threadIdx.x & 63;
    const int wv   = threadIdx.x >> 6;     // 0..7
    const int rb   = blockIdx.y * 8 + wv;  // row-block 0..63

    float acc[RB];
    #pragma unroll
    for (int r = 0; r < RB; r++) acc[r] = 0.0f;

    #pragma unroll 1
    for (int ch = 0; ch < S1_CH; ch++) {
        __syncthreads();
        {   // stage x tile (64 b x 32 c), coalesced along c
            int cc = threadIdx.x & 31;
            int bb = threadIdx.x >> 5;     // 0..15
            #pragma unroll
            for (int k = 0; k < 4; k++) {
                int bbb = bb + 16 * k;
                xs[bbb][cc] = x[(size_t)(tile * 64 + bbb) * IN_DIM + ch * C + cc];
            }
        }
        __syncthreads();
        #pragma unroll
        for (int j = 0; j < 4; j++) {
            int c = wv * 4 + j;
            write_acts(As, c, lane, w * xs[lane][c]);
        }
        __syncthreads();
        EDGE_LOOP(seg1, rb * S1_CH + ch)
    }

    const int b = tile * 64 + lane;
    const int row0 = rb * RB;
    #pragma unroll
    for (int r = 0; r < RB; r++)
        hidden_t[(size_t)(row0 + r) * BATCH + b] = __float2bfloat16(acc[r]);
}

// ---------------------------------------------------------------------------
// Stage 2: block = 512 thr = 8 waves x 32 rows = all 256 out rows.
// Grid (128 tiles, 4 chunk groups of 24). fp32 atomicAdd partials into d_out.
// ---------------------------------------------------------------------------
__global__ __launch_bounds__(512, 4) void k_out(const float* __restrict__ x,
                                                const __hip_bfloat16* __restrict__ hidden_t,
                                                const float* __restrict__ wp,
                                                const uint4* __restrict__ seg2,
                                                float* __restrict__ out) {
    __shared__ float As[4 * C * 64];
    __shared__ float xs[64][C + 1];

    const float w  = wp[0];
    const int tile = blockIdx.x;           // 0..127
    const int cg   = blockIdx.y;           // 0..3
    const int lane = threadIdx.x & 63;
    const int wv   = threadIdx.x >> 6;     // 0..7 (= row-block)

    float acc[RB];
    #pragma unroll
    for (int r = 0; r < RB; r++) acc[r] = 0.0f;

    #pragma unroll 1
    for (int cj = 0; cj < 24; cj++) {
        int ch   = cg * 24 + cj;
        int col0 = ch * C;
        __syncthreads();
        if (col0 < IN_DIM) {               // x region: coalesced along c
            int cc = threadIdx.x & 31;
            int bb = threadIdx.x >> 5;
            #pragma unroll
            for (int k = 0; k < 4; k++) {
                int bbb = bb + 16 * k;
                xs[bbb][cc] = x[(size_t)(tile * 64 + bbb) * IN_DIM + col0 + cc];
            }
        } else {                           // hidden_t region: coalesced along b
            int bb = threadIdx.x & 63;
            int c0 = threadIdx.x >> 6;     // 0..7
            #pragma unroll
            for (int k = 0; k < 4; k++) {
                int c = c0 + 8 * k;
                xs[bb][c] = __bfloat162float(
                    hidden_t[(size_t)(col0 - IN_DIM + c) * BATCH + tile * 64 + bb]);
            }
        }
        __syncthreads();
        #pragma unroll
        for (int j = 0; j < 4; j++) {
            int c = wv * 4 + j;
            write_acts(As, c, lane, w * xs[lane][c]);
        }
        __syncthreads();
        EDGE_LOOP(seg2, wv * S2_CH + ch)
    }

    const int b = tile * 64 + lane;
    #pragma unroll
    for (int r = 0; r < RB; r++)
        atomicAdd(&out[(size_t)b * OUT_DIM + wv * RB + r], acc[r]);
}

// ---------------------------------------------------------------------------
extern "C" void kernel_launch(void* const* d_in, const int* in_sizes, int n_in,
                              void* d_out, int out_size, void* d_ws, size_t ws_size,
                              hipStream_t stream) {
    const float* x   = (const float*)d_in[0];
    const float* w   = (const float*)d_in[1];
    const int*   mat = (const int*)d_in[2];
    float* out = (float*)d_out;

    uint8_t* ws = (uint8_t*)d_ws;
    __hip_bfloat16* hidden_t = (__hip_bfloat16*)ws;               // 33.55 MB
    uint4* seg1 = (uint4*)(ws + (size_t)BATCH * N_HID * 2);       // 1.05 MB
    uint4* seg2 = seg1 + (size_t)S1_RB * S1_CH * RB;              // 0.39 MB
    (void)ws_size; (void)in_sizes; (void)n_in;

    hipMemsetAsync(d_out, 0, (size_t)out_size * sizeof(float), stream);

    {
        int nwaves = N_HID * (IN_DIM / 64) + OUT_DIM * (SRC_DIM / 64); // 45056
        k_prep<<<nwaves / 4, 256, 0, stream>>>(mat, seg1, seg2);
    }
    {
        dim3 g(BATCH / 64, 8);             // 1024 blocks
        k_hid<<<g, 512, 0, stream>>>(x, w, seg1, hidden_t);
    }
    {
        dim3 g(BATCH / 64, 4);             // 512 blocks
        k_out<<<g, 512, 0, stream>>>(x, hidden_t, w, seg2, out);
    }
}

// Round 3
// 516.451 us; speedup vs baseline: 43.7701x; 1.9579x over previous
//
#include <hip/hip_runtime.h>
#include <hip/hip_bf16.h>
#include <stdint.h>

// Problem constants
#define BATCH   8192
#define IN_DIM  1024
#define N_HID   2048
#define OUT_DIM 256
#define SRC_DIM 3072

// Tiling
#define C     32                   // source columns per chunk
#define RB    32                   // rows per row-block (= rows per wave)
#define S1_CH (IN_DIM / C)         // 32
#define S1_RB (N_HID / RB)         // 64
#define S2_CH (SRC_DIM / C)        // 96
#define S2_RB (OUT_DIM / RB)       // 8
#define NSEG1 (S1_RB * S1_CH)      // 2048
#define NSEG2 (S2_RB * S2_CH)      // 768
#define MAXW  8                    // max 4-slot record planes per row (n<=32)
#define SEG_U32 (MAXW * RB)        // 256 u32 per segment (1 KB)
#define ZSLOT 128                  // A-tile zero page slot (pad byte 0x80)

// ---------------------------------------------------------------------------
// k_prep: one wave per (row-block, chunk) segment. Lane r (<32) scans its
// row's 32 codes and scatters slot bytes (t*32+c) into plane-major records:
// rec[p][r] u32 = 4 slot bytes (little-endian = edges 4p..4p+3 of row r).
// Pad bytes come from the 0x80 memset. hdr = W = ceil(max_n / 4).
// ---------------------------------------------------------------------------
__global__ void k_prep(const int* __restrict__ mat,
                       uint32_t* __restrict__ seg1, uint32_t* __restrict__ seg2,
                       uint32_t* __restrict__ hdr1, uint32_t* __restrict__ hdr2) {
    int wid  = (blockIdx.x * blockDim.x + threadIdx.x) >> 6;
    int lane = threadIdx.x & 63;
    if (wid >= NSEG1 + NSEG2) return;

    int row0, col0;
    uint32_t *seg, *hdr;
    if (wid < NSEG1) {
        int rb = wid / S1_CH, ch = wid % S1_CH;
        row0 = rb * RB;          col0 = ch * C;
        seg = seg1 + (size_t)wid * SEG_U32;  hdr = hdr1 + wid;
    } else {
        int s  = wid - NSEG1;
        int rb = s / S2_CH, ch = s % S2_CH;
        row0 = N_HID + rb * RB;  col0 = ch * C;
        seg = seg2 + (size_t)s * SEG_U32;    hdr = hdr2 + s;
    }

    int n = 0;
    if (lane < RB) {
        const int* mrow = mat + (size_t)(row0 + lane) * SRC_DIM + col0;
        uint8_t* sb = (uint8_t*)seg;
        for (int c = 0; c < C; c++) {
            int code = mrow[c];
            if (code != 0) {
                sb[(size_t)(n >> 2) * (RB * 4) + lane * 4 + (n & 3)] =
                    (uint8_t)((code - 1) * C + c);
                n++;
            }
        }
    }
    int m = n;
    #pragma unroll
    for (int d = 1; d < 64; d <<= 1) m = max(m, __shfl_xor(m, d));
    if (lane == 0) *hdr = (uint32_t)((m + 3) >> 2);
}

// A-tile: As[slot*64 + lane], slot = t*32+c (0..127); slot 128 = zero page.
__device__ __forceinline__ void write_acts(float* As, int c, int lane, float v) {
    float e2 = __expf(2.0f * v);
    float en = __expf(-v);
    As[(0 * C + c) * 64 + lane] = v;
    As[(1 * C + c) * 64 + lane] = fmaxf(v, 0.0f);
    As[(2 * C + c) * 64 + lane] = 1.0f - 2.0f / (e2 + 1.0f);   // tanh
    As[(3 * C + c) * 64 + lane] = 1.0f / (1.0f + en);          // sigmoid
}

// Branchless plane-0 (128 independent ds_reads, schedulable straight-line);
// overflow planes p>=1 gated per-row by a wave-uniform all-pad check.
#define EDGE_PLANES(SEGBASE, WVAL)                                             \
    {                                                                          \
        const uint32_t* rec_ = (SEGBASE);                                      \
        _Pragma("unroll")                                                      \
        for (int r = 0; r < RB; r++) {                                         \
            uint32_t g = rec_[r];                                              \
            float a = acc[r];                                                  \
            a += As[(g & 255u) * 64 + lane];                                   \
            a += As[((g >> 8) & 255u) * 64 + lane];                            \
            a += As[((g >> 16) & 255u) * 64 + lane];                           \
            a += As[(g >> 24) * 64 + lane];                                    \
            acc[r] = a;                                                        \
        }                                                                      \
        for (uint32_t p = 1; p < (WVAL); p++) {                                \
            const uint32_t* rp_ = rec_ + p * RB;                               \
            _Pragma("unroll")                                                  \
            for (int r = 0; r < RB; r++) {                                     \
                uint32_t g = rp_[r];                                           \
                if (g != 0x80808080u) {                                        \
                    float a = acc[r];                                          \
                    a += As[(g & 255u) * 64 + lane];                           \
                    a += As[((g >> 8) & 255u) * 64 + lane];                    \
                    a += As[((g >> 16) & 255u) * 64 + lane];                   \
                    a += As[(g >> 24) * 64 + lane];                            \
                    acc[r] = a;                                                \
                }                                                              \
            }                                                                  \
        }                                                                      \
    }

// ---------------------------------------------------------------------------
// Stage 1: block = 512 thr = 8 waves x 32 rows; lanes = 64 batch.
// Grid (128 batch tiles, 8 row splits). hidden stored transposed [row][batch].
// ---------------------------------------------------------------------------
__global__ __launch_bounds__(512, 4) void k_hid(const float* __restrict__ x,
                                                const float* __restrict__ wp,
                                                const uint32_t* __restrict__ seg1,
                                                const uint32_t* __restrict__ hdr1,
                                                __hip_bfloat16* __restrict__ hidden_t) {
    __shared__ float As[(4 * C + 1) * 64];   // 33 KB (incl. zero page)
    __shared__ float xs[64][C + 1];          // 8.4 KB

    const float w  = wp[0];
    const int tile = blockIdx.x;
    const int lane = threadIdx.x & 63;
    const int wv   = __builtin_amdgcn_readfirstlane(threadIdx.x >> 6); // 0..7
    const int rb   = blockIdx.y * 8 + wv;                              // 0..63

    if (threadIdx.x < 64) As[ZSLOT * 64 + threadIdx.x] = 0.0f;

    float acc[RB];
    #pragma unroll
    for (int r = 0; r < RB; r++) acc[r] = 0.0f;

    #pragma unroll 1
    for (int ch = 0; ch < S1_CH; ch++) {
        __syncthreads();
        {   // stage x tile (64 b x 32 c), coalesced along c
            int cc = threadIdx.x & 31;
            int bb = threadIdx.x >> 5;
            #pragma unroll
            for (int k = 0; k < 4; k++) {
                int bbb = bb + 16 * k;
                xs[bbb][cc] = x[(size_t)(tile * 64 + bbb) * IN_DIM + ch * C + cc];
            }
        }
        __syncthreads();
        #pragma unroll
        for (int j = 0; j < 4; j++) {
            int c = wv * 4 + j;
            write_acts(As, c, lane, w * xs[lane][c]);
        }
        __syncthreads();
        int sidx = rb * S1_CH + ch;
        uint32_t W = hdr1[sidx];
        EDGE_PLANES(seg1 + (size_t)sidx * SEG_U32, W)
    }

    const int b = tile * 64 + lane;
    const int row0 = rb * RB;
    #pragma unroll
    for (int r = 0; r < RB; r++)
        hidden_t[(size_t)(row0 + r) * BATCH + b] = __float2bfloat16(acc[r]);
}

// ---------------------------------------------------------------------------
// Stage 2: block = 512 thr = 8 waves x 32 rows = all 256 out rows.
// Grid (128 tiles, 4 chunk groups of 24). Coalesced fp32 partials [cg][r][b].
// ---------------------------------------------------------------------------
__global__ __launch_bounds__(512, 4) void k_out(const float* __restrict__ x,
                                                const __hip_bfloat16* __restrict__ hidden_t,
                                                const float* __restrict__ wp,
                                                const uint32_t* __restrict__ seg2,
                                                const uint32_t* __restrict__ hdr2,
                                                float* __restrict__ partials) {
    __shared__ float As[(4 * C + 1) * 64];
    __shared__ float xs[64][C + 1];

    const float w  = wp[0];
    const int tile = blockIdx.x;
    const int cg   = blockIdx.y;             // 0..3
    const int lane = threadIdx.x & 63;
    const int wv   = __builtin_amdgcn_readfirstlane(threadIdx.x >> 6); // 0..7

    if (threadIdx.x < 64) As[ZSLOT * 64 + threadIdx.x] = 0.0f;

    float acc[RB];
    #pragma unroll
    for (int r = 0; r < RB; r++) acc[r] = 0.0f;

    #pragma unroll 1
    for (int cj = 0; cj < 24; cj++) {
        int ch   = cg * 24 + cj;
        int col0 = ch * C;
        __syncthreads();
        if (col0 < IN_DIM) {                 // x region: coalesced along c
            int cc = threadIdx.x & 31;
            int bb = threadIdx.x >> 5;
            #pragma unroll
            for (int k = 0; k < 4; k++) {
                int bbb = bb + 16 * k;
                xs[bbb][cc] = x[(size_t)(tile * 64 + bbb) * IN_DIM + col0 + cc];
            }
        } else {                             // hidden_t: coalesced along b
            int bb = threadIdx.x & 63;
            int c0 = threadIdx.x >> 6;
            #pragma unroll
            for (int k = 0; k < 4; k++) {
                int c = c0 + 8 * k;
                xs[bb][c] = __bfloat162float(
                    hidden_t[(size_t)(col0 - IN_DIM + c) * BATCH + tile * 64 + bb]);
            }
        }
        __syncthreads();
        #pragma unroll
        for (int j = 0; j < 4; j++) {
            int c = wv * 4 + j;
            write_acts(As, c, lane, w * xs[lane][c]);
        }
        __syncthreads();
        int sidx = wv * S2_CH + ch;
        uint32_t W = hdr2[sidx];
        EDGE_PLANES(seg2 + (size_t)sidx * SEG_U32, W)
    }

    // coalesced partial store: partials[cg][row][batch]
    #pragma unroll
    for (int r = 0; r < RB; r++)
        partials[((size_t)cg * OUT_DIM + wv * RB + r) * BATCH + tile * 64 + lane] = acc[r];
}

// ---------------------------------------------------------------------------
// k_sum: reduce 4 partial planes + transpose [r][b] -> out[b][r] (float4).
// Block 256 thr handles 64 b x 16 r.  Grid (128, 16).
// ---------------------------------------------------------------------------
__global__ __launch_bounds__(256) void k_sum(const float* __restrict__ partials,
                                             float* __restrict__ out) {
    __shared__ float t[16][65];
    const int b0 = blockIdx.x * 64, r0 = blockIdx.y * 16;
    const int lane = threadIdx.x & 63;
    const int g4   = threadIdx.x >> 6;      // 0..3

    #pragma unroll
    for (int k = 0; k < 4; k++) {
        int rr = g4 * 4 + k;                // 0..15
        float s = 0.0f;
        #pragma unroll
        for (int cg = 0; cg < 4; cg++)
            s += partials[((size_t)cg * OUT_DIM + r0 + rr) * BATCH + b0 + lane];
        t[rr][lane] = s;
    }
    __syncthreads();
    int bb = threadIdx.x >> 2, rq = threadIdx.x & 3;
    float4 v;
    v.x = t[rq * 4 + 0][bb];
    v.y = t[rq * 4 + 1][bb];
    v.z = t[rq * 4 + 2][bb];
    v.w = t[rq * 4 + 3][bb];
    *(float4*)&out[(size_t)(b0 + bb) * OUT_DIM + r0 + rq * 4] = v;
}

// ---------------------------------------------------------------------------
extern "C" void kernel_launch(void* const* d_in, const int* in_sizes, int n_in,
                              void* d_out, int out_size, void* d_ws, size_t ws_size,
                              hipStream_t stream) {
    const float* x   = (const float*)d_in[0];
    const float* w   = (const float*)d_in[1];
    const int*   mat = (const int*)d_in[2];
    float* out = (float*)d_out;

    uint8_t* ws = (uint8_t*)d_ws;
    size_t off = 0;
    __hip_bfloat16* hidden_t = (__hip_bfloat16*)(ws + off); off += (size_t)BATCH * N_HID * 2;        // 33.55 MB
    uint32_t* seg1 = (uint32_t*)(ws + off); off += (size_t)NSEG1 * SEG_U32 * 4;                      //  2.10 MB
    uint32_t* seg2 = (uint32_t*)(ws + off); off += (size_t)NSEG2 * SEG_U32 * 4;                      //  0.79 MB
    uint32_t* hdr1 = (uint32_t*)(ws + off); off += (size_t)NSEG1 * 4;
    uint32_t* hdr2 = (uint32_t*)(ws + off); off += (size_t)NSEG2 * 4;
    float* partials = (float*)(ws + off);   off += (size_t)4 * OUT_DIM * BATCH * 4;                  // 33.55 MB
    (void)ws_size; (void)in_sizes; (void)n_in; (void)out_size;

    // pad-fill both seg regions (contiguous) with 0x80 slot bytes
    hipMemsetAsync(seg1, 0x80, (size_t)(NSEG1 + NSEG2) * SEG_U32 * 4, stream);

    {
        int nseg = NSEG1 + NSEG2;                   // 2816 waves
        k_prep<<<(nseg + 3) / 4, 256, 0, stream>>>(mat, seg1, seg2, hdr1, hdr2);
    }
    {
        dim3 g(BATCH / 64, 8);                      // 1024 blocks
        k_hid<<<g, 512, 0, stream>>>(x, w, seg1, hdr1, hidden_t);
    }
    {
        dim3 g(BATCH / 64, 4);                      // 512 blocks
        k_out<<<g, 512, 0, stream>>>(x, hidden_t, w, seg2, hdr2, partials);
    }
    {
        dim3 g(BATCH / 64, OUT_DIM / 16);           // 2048 blocks
        k_sum<<<g, 256, 0, stream>>>(partials, out);
    }
}